// Round 13
// baseline (516.989 us; speedup 1.0000x reference)
//
#include <hip/hip_runtime.h>
#include <stdint.h>

#define Hh    51
#define Bsz   1024
#define Tin   512
#define Ttot  576      // Tin + future(64)
#define NBB   8        // batches per block (grid 128)
#define BROWS 8        // LDS batch rows (mirror trick: cols 8-15 read row nn&7)
#define NTP   7        // tile-pairs (13 M-tiles in 7 pairs)
#define NWV   14       // 7 L2 waves + 7 L1 waves (layer-split specialization)
#define BLK   (NWV*64) // 896
#define BST   136      // per-batch k-stride (uint16) = 68 dwords
#define WS    18       // wsum per-wave stride (16 partials + 2 pad)

#define L2E   1.4426950408889634f    // log2(e)
#define TL2E  2.8853900817779268f    // 2*log2(e)

typedef __attribute__((ext_vector_type(8))) _Float16 half8;  // 8 x f16 frag
typedef __attribute__((ext_vector_type(4))) float f32x4;     // C/D frag

__device__ __forceinline__ float rcpf(float x){ return __builtin_amdgcn_rcpf(x); }
__device__ __forceinline__ float exp2f_fast(float x){
#if __has_builtin(__builtin_amdgcn_exp2f)
    return __builtin_amdgcn_exp2f(x);
#else
    return exp2f(x);
#endif
}

// Fused LSTM pointwise, rcp-merged: 7 trans ops.
// Inputs pre-scaled: vi,vf,vo by log2e; vg by 2log2e. Updates c, returns h.
__device__ __forceinline__ float cell_fuse(float vi, float vf, float vg,
                                           float vo, float& c){
    float Ei = exp2f_fast(-vi), Ef = exp2f_fast(-vf), Eg = exp2f_fast(-vg);
    float A = 1.f + Ef, B = 1.f + Ei, C = 1.f + Eg, D = 1.f - Eg;
    float BC = B*C;
    float R  = rcpf(A*BC);
    float cn = __builtin_fmaf(c, BC*R, (A*D)*R);
    c = cn;
    float Ec = exp2f_fast(fminf(-cn*TL2E, 120.f));
    float Eo = exp2f_fast(-vo);
    float R2 = rcpf((1.f+Eo)*(1.f+Ec));
    return (1.f - Ec) * R2;
}

__device__ __forceinline__ uint16_t f2h(float f){
    union{ _Float16 h; uint16_t u; } v; v.h = (_Float16)f;   // v_cvt_f16_f32 RNE
    return v.u;
}

// qsum: sum over lanes ^16 and ^32 on the VALU pipe (permlane swaps, R12-
// proven); fallback = proven shfl chain. Same pair-sum order either way.
__device__ __forceinline__ float qsum(float x){
#if __has_builtin(__builtin_amdgcn_permlane16_swap) && __has_builtin(__builtin_amdgcn_permlane32_swap)
    unsigned int xi = __float_as_uint(x);
    auto p = __builtin_amdgcn_permlane16_swap(xi, xi, false, false);
    float s = __uint_as_float(p[0]) + __uint_as_float(p[1]);
    unsigned int si = __float_as_uint(s);
    auto q = __builtin_amdgcn_permlane32_swap(si, si, false, false);
    return __uint_as_float(q[0]) + __uint_as_float(q[1]);
#else
    x += __shfl_xor(x, 16, 64);
    x += __shfl_xor(x, 32, 64);
    return x;
#endif
}
#define MFMA __builtin_amdgcn_mfma_f32_16x16x32_f16

// R27 = R12 + out-writer moved from wave 6 (L2, heaviest: 4 slabs, 8 MFMA,
// cell, qsum) to wave 13 (L1, lightest: 2 slabs, 4 MFMA -- half dummy).
// The osum block (14 stride-18 LDS reads + 13-add chain + global store,
// ~100-150cy) sat on the barrier quantum via wave 6 every step; on wave 13
// it overlaps the L2 waves' longer chain (input loop) / the L2-only phase 1
// (future loop). No numerics change (same reads/adds/store, different wave).
__global__ __launch_bounds__(BLK, 1)
void lstm_f16q(const float* __restrict__ inp,    // [B, Tin]
               const float* __restrict__ Wih1,   // [204, 1]
               const float* __restrict__ Whh1,   // [204, 51]
               const float* __restrict__ bih1,   // [204]
               const float* __restrict__ bhh1,   // [204]
               const float* __restrict__ Wih2,   // [204, 51]
               const float* __restrict__ Whh2,   // [204, 51]
               const float* __restrict__ bih2,   // [204]
               const float* __restrict__ bhh2,   // [204]
               const float* __restrict__ Wl,     // [1, 51]
               const float* __restrict__ blp,    // [1]
               float* __restrict__ outp)         // [B, Ttot]
{
    const int tid = threadIdx.x;
    const int wv  = tid >> 6, ln = tid & 63;
    const int quad = ln >> 4, nn = ln & 15;
    const bool lo = (nn < 8);
    const int ba  = nn & 7;            // batch owned/read by this lane
    const int b0  = blockIdx.x * NBB;
    const bool isL2 = (wv < NTP);      // role: L2(t) vs L1(t+1)
    const int  wvv  = isL2 ? wv : wv - NTP;

    __shared__ __align__(16) uint16_t Bh[2][BROWS*BST];
    __shared__ float wsum[2][NTP*WS];     // parity-dbuf output partials

    for (int k = tid; k < BROWS*BST; k += BLK) { Bh[0][k] = 0; Bh[1][k] = 0; }
    if (tid < NTP*WS) { wsum[0][tid] = 0.f; wsum[1][tid] = 0.f; }

    // ---- A fragments, role-unioned: L2 uses af[tl*4+s] (s=0..3, Wih2|Whh2);
    // L1 uses af[tl*2+s] (s=0..1, Whh1). bs = role bias; w1v/wlu role-only. ----
    half8 af[8];
    f32x4 bs[2], w1v[2];
    float wlu[2];
#pragma unroll
    for (int tl = 0; tl < 2; ++tl) {
        const bool tv = (wvv + 7*tl) < 13;
        const int lr = 16*(wvv + 7*tl) + nn;
        const int ua_ = lr >> 2, ga = lr & 3;
        const bool av = tv && (ua_ < Hh);
        const int pr = av ? (ga*Hh + ua_) : 0;
        const float rs = (ga == 2) ? TL2E : L2E;
        if (isL2) {
#pragma unroll
            for (int s = 0; s < 4; ++s)
#pragma unroll
                for (int j = 0; j < 8; ++j) {
                    int k = 32*s + quad*8 + j;
                    float w = 0.f;
                    if (av) {
                        if (k < Hh)                    w = Wih2[pr*Hh + k]*rs;
                        else if (k >= 64 && k < 64+Hh) w = Whh2[pr*Hh + (k-64)]*rs;
                    }
                    af[tl*4+s][j] = (_Float16)w;
                }
        } else {
#pragma unroll
            for (int s = 0; s < 2; ++s)
#pragma unroll
                for (int j = 0; j < 8; ++j) {
                    int k = 32*s + quad*8 + j;
                    float w = (av && k < Hh) ? Whh1[pr*Hh + k]*rs : 0.f;
                    af[tl*2+s][j] = (_Float16)w;
                }
        }
        const int u = 4*(wvv + 7*tl) + quad;
        const bool uv = tv && (u < Hh);
#pragma unroll
        for (int i = 0; i < 4; ++i) {
            int pri = uv ? (i*Hh + u) : 0;
            float gs = (i == 2) ? TL2E : L2E;
            if (isL2) {
                bs[tl][i]  = uv ? (bih2[pri] + bhh2[pri])*gs : 0.f;
                w1v[tl][i] = 0.f;
            } else {
                bs[tl][i]  = uv ? (bih1[pri] + bhh1[pri])*gs : 0.f;
                w1v[tl][i] = uv ? Wih1[pri]*gs : 0.f;
            }
        }
        wlu[tl] = (isL2 && uv) ? Wl[u] : 0.f;
    }
    const float blv = blp[0];

    // ---- assigned cell for this lane: (ua, ba); role c-state lives here ----
    const int  ua  = 4*(wvv + (lo ? 0 : 7)) + quad;
    const bool uva = (ua < Hh);
    const float wlua = lo ? wlu[0] : wlu[1];
    float cst = 0.f;                    // c2 for L2 waves, c1 for L1 waves

    // ---- prologue: h1(0) by L1 waves (they own c1) ----
    if (!isL2) {
        float b1a[4], w1a[4];
#pragma unroll
        for (int i = 0; i < 4; ++i) {
            b1a[i] = lo ? bs[0][i] : bs[1][i];
            w1a[i] = lo ? w1v[0][i] : w1v[1][i];
        }
        float x0 = inp[(size_t)(b0 + ba)*Tin];
        float vi = __builtin_fmaf(w1a[0], x0, b1a[0]);
        float vf = __builtin_fmaf(w1a[1], x0, b1a[1]);
        float vg = __builtin_fmaf(w1a[2], x0, b1a[2]);
        float vo = __builtin_fmaf(w1a[3], x0, b1a[3]);
        float h1n = cell_fuse(vi, vf, vg, vo, cst);
        if (uva) Bh[0][ba*BST + ua] = f2h(h1n);
    }
    float xreg = (!isL2 && Tin > 1) ? inp[(size_t)(b0 + ba)*Tin + 1] : 0.f;
    __syncthreads();

    // ================= input-mode loop: t in [0, Tin-1) =================
    for (int t = 0; t < Tin-1; ++t) {
        const int cur = t & 1, nxt = cur ^ 1;

        // ---- B-frag reads first; L1 waves only need slabs 0,1 ----
        const uint16_t* rb = &Bh[cur][ba*BST + quad*8];
        half8 s0 = *(const half8*)(rb), s1 = *(const half8*)(rb + 32);
        half8 s2, s3;
        if (isL2) { s2 = *(const half8*)(rb + 64); s3 = *(const half8*)(rb + 96); }

        // out(t-1) write (wave 13: lightest L1 wave; overlaps L2 chains)
        if (wv == NWV-1 && t > 0) {
            float osum = blv;
#pragma unroll
            for (int w = 0; w < NTP; ++w)
                osum += wsum[nxt][w*WS + ba] + wsum[nxt][w*WS + 8 + ba];
            if (ln < NBB) outp[(size_t)(b0 + ln)*Ttot + (t-1)] = osum;
        }
        float xn = (!isL2 && t + 2 < Tin) ? inp[(size_t)(b0 + ba)*Tin + t + 2] : 0.f;

        if (isL2) {
            // ---- L2(t): 8 MFMA, h2 cell, wsum partial ----
            f32x4 aA0 = bs[0], aB0 = {0.f,0.f,0.f,0.f};
            f32x4 aA1 = bs[1], aB1 = {0.f,0.f,0.f,0.f};
            aA0 = MFMA(af[0], s0, aA0, 0,0,0);  aB0 = MFMA(af[1], s1, aB0, 0,0,0);
            aA1 = MFMA(af[4], s0, aA1, 0,0,0);  aB1 = MFMA(af[5], s1, aB1, 0,0,0);
            aA0 = MFMA(af[2], s2, aA0, 0,0,0);  aB0 = MFMA(af[3], s3, aB0, 0,0,0);
            aA1 = MFMA(af[6], s2, aA1, 0,0,0);  aB1 = MFMA(af[7], s3, aB1, 0,0,0);
            f32x4 gt0 = aA0 + aB0, gt1 = aA1 + aB1;
            float g[4];
#pragma unroll
            for (int i = 0; i < 4; ++i) g[i] = lo ? gt0[i] : gt1[i];
            float h2v = cell_fuse(g[0], g[1], g[2], g[3], cst);
            if (uva) Bh[nxt][ba*BST + 64 + ua] = f2h(h2v);
            float part = qsum(wlua * h2v);
            if (ln < 16) wsum[cur][wvv*WS + ln] = part;
        } else {
            // ---- L1(t+1): 4 MFMA, h1 cell ----
            f32x4 bA0, bA1, bB0 = {0.f,0.f,0.f,0.f}, bB1 = {0.f,0.f,0.f,0.f};
#pragma unroll
            for (int i = 0; i < 4; ++i) {
                bA0[i] = __builtin_fmaf(w1v[0][i], xreg, bs[0][i]);
                bA1[i] = __builtin_fmaf(w1v[1][i], xreg, bs[1][i]);
            }
            bA0 = MFMA(af[0], s0, bA0, 0,0,0);  bB0 = MFMA(af[1], s1, bB0, 0,0,0);
            bA1 = MFMA(af[2], s0, bA1, 0,0,0);  bB1 = MFMA(af[3], s1, bB1, 0,0,0);
            f32x4 gt0 = bA0 + bB0, gt1 = bA1 + bB1;
            float g[4];
#pragma unroll
            for (int i = 0; i < 4; ++i) g[i] = lo ? gt0[i] : gt1[i];
            float h1v = cell_fuse(g[0], g[1], g[2], g[3], cst);
            if (uva) Bh[nxt][ba*BST + ua] = f2h(h1v);
        }

        __syncthreads();
        xreg = xn;
    }

    // ================= future loop: t in [Tin-1, Ttot) =================
    for (int t = Tin-1; t < Ttot; ++t) {
        const int cur = t & 1, nxt = cur ^ 1;

        const uint16_t* rb = &Bh[cur][ba*BST + quad*8];
        half8 s0 = *(const half8*)(rb), s1 = *(const half8*)(rb + 32);
        half8 s2, s3;
        if (isL2) { s2 = *(const half8*)(rb + 64); s3 = *(const half8*)(rb + 96); }

        // out(t-1) by wave 13 -- L1 role idles in phase 1, free overlap
        if (wv == NWV-1) {      // t >= 511 > 0 always
            float osum = blv;
#pragma unroll
            for (int w = 0; w < NTP; ++w)
                osum += wsum[nxt][w*WS + ba] + wsum[nxt][w*WS + 8 + ba];
            if (ln < NBB) outp[(size_t)(b0 + ln)*Ttot + (t-1)] = osum;
        }

        if (isL2) {
            f32x4 aA0 = bs[0], aB0 = {0.f,0.f,0.f,0.f};
            f32x4 aA1 = bs[1], aB1 = {0.f,0.f,0.f,0.f};
            aA0 = MFMA(af[0], s0, aA0, 0,0,0);  aB0 = MFMA(af[1], s1, aB0, 0,0,0);
            aA1 = MFMA(af[4], s0, aA1, 0,0,0);  aB1 = MFMA(af[5], s1, aB1, 0,0,0);
            aA0 = MFMA(af[2], s2, aA0, 0,0,0);  aB0 = MFMA(af[3], s3, aB0, 0,0,0);
            aA1 = MFMA(af[6], s2, aA1, 0,0,0);  aB1 = MFMA(af[7], s3, aB1, 0,0,0);
            f32x4 gt0 = aA0 + aB0, gt1 = aA1 + aB1;
            float g[4];
#pragma unroll
            for (int i = 0; i < 4; ++i) g[i] = lo ? gt0[i] : gt1[i];
            float h2v = cell_fuse(g[0], g[1], g[2], g[3], cst);
            if (uva) Bh[nxt][ba*BST + 64 + ua] = f2h(h2v);
            float part = qsum(wlua * h2v);
            if (ln < 16) wsum[cur][wvv*WS + ln] = part;
        }
        __syncthreads();                                   // bar 1

        if (t + 1 < Ttot) {
            if (!isL2) {
                // x(t+1) = out(t) from wsum[cur], then L1(t+1)
                float osum = blv;
#pragma unroll
                for (int w = 0; w < NTP; ++w)
                    osum += wsum[cur][w*WS + ba] + wsum[cur][w*WS + 8 + ba];
                f32x4 bA0, bA1, bB0 = {0.f,0.f,0.f,0.f}, bB1 = {0.f,0.f,0.f,0.f};
#pragma unroll
                for (int i = 0; i < 4; ++i) {
                    bA0[i] = __builtin_fmaf(w1v[0][i], osum, bs[0][i]);
                    bA1[i] = __builtin_fmaf(w1v[1][i], osum, bs[1][i]);
                }
                bA0 = MFMA(af[0], s0, bA0, 0,0,0);  bB0 = MFMA(af[1], s1, bB0, 0,0,0);
                bA1 = MFMA(af[2], s0, bA1, 0,0,0);  bB1 = MFMA(af[3], s1, bB1, 0,0,0);
                f32x4 gt0 = bA0 + bB0, gt1 = bA1 + bB1;
                float g[4];
#pragma unroll
                for (int i = 0; i < 4; ++i) g[i] = lo ? gt0[i] : gt1[i];
                float h1v = cell_fuse(g[0], g[1], g[2], g[3], cst);
                if (uva) Bh[nxt][ba*BST + ua] = f2h(h1v);
            }
            __syncthreads();                               // bar 2 (future only)
        }
    }

    // final output (t = Ttot-1): wsum[(Ttot-1)&1] visible after last bar 1
    if (wv == NWV-1) {
        float osum = blv;
#pragma unroll
        for (int w = 0; w < NTP; ++w)
            osum += wsum[(Ttot-1)&1][w*WS + ba] + wsum[(Ttot-1)&1][w*WS + 8 + ba];
        if (ln < NBB) outp[(size_t)(b0 + ln)*Ttot + (Ttot-1)] = osum;
    }
}

extern "C" void kernel_launch(void* const* d_in, const int* in_sizes, int n_in,
                              void* d_out, int out_size, void* d_ws, size_t ws_size,
                              hipStream_t stream) {
    (void)in_sizes; (void)n_in; (void)out_size; (void)d_ws; (void)ws_size;
    lstm_f16q<<<dim3(Bsz / NBB), dim3(BLK), 0, stream>>>(
        (const float*)d_in[0], (const float*)d_in[1],
        (const float*)d_in[2], (const float*)d_in[3],
        (const float*)d_in[4], (const float*)d_in[5],
        (const float*)d_in[6], (const float*)d_in[7],
        (const float*)d_in[8], (const float*)d_in[9],
        (const float*)d_in[10], (float*)d_out);
}

// Round 14
// 486.057 us; speedup vs baseline: 1.0636x; 1.0636x over previous
//
#include <hip/hip_runtime.h>
#include <stdint.h>

#define Hh    51
#define Bsz   1024
#define Tin   512
#define Ttot  576      // Tin + future(64)
#define NBB   8        // batches per block (grid 128)
#define BROWS 8        // LDS batch rows (mirror trick: cols 8-15 read row nn&7)
#define NTP   7        // tile-pairs (13 M-tiles in 7 pairs)
#define NWV   14       // 7 L2 waves + 7 L1 waves (layer-split specialization)
#define BLK   (NWV*64) // 896
#define BST   136      // per-batch k-stride (uint16) = 68 dwords
#define WS    18       // wsum per-wave stride (16 partials + 2 pad)
#define OUTW  11       // out-writer wave: L1 role, SIMD3 (lightest: waves 3,7,11)

#define L2E   1.4426950408889634f    // log2(e)
#define TL2E  2.8853900817779268f    // 2*log2(e)

typedef __attribute__((ext_vector_type(8))) _Float16 half8;  // 8 x f16 frag
typedef __attribute__((ext_vector_type(4))) float f32x4;     // C/D frag

__device__ __forceinline__ float rcpf(float x){ return __builtin_amdgcn_rcpf(x); }
__device__ __forceinline__ float exp2f_fast(float x){
#if __has_builtin(__builtin_amdgcn_exp2f)
    return __builtin_amdgcn_exp2f(x);
#else
    return exp2f(x);
#endif
}

// Fused LSTM pointwise, rcp-merged: 7 trans ops.
// Inputs pre-scaled: vi,vf,vo by log2e; vg by 2log2e. Updates c, returns h.
__device__ __forceinline__ float cell_fuse(float vi, float vf, float vg,
                                           float vo, float& c){
    float Ei = exp2f_fast(-vi), Ef = exp2f_fast(-vf), Eg = exp2f_fast(-vg);
    float A = 1.f + Ef, B = 1.f + Ei, C = 1.f + Eg, D = 1.f - Eg;
    float BC = B*C;
    float R  = rcpf(A*BC);
    float cn = __builtin_fmaf(c, BC*R, (A*D)*R);
    c = cn;
    float Ec = exp2f_fast(fminf(-cn*TL2E, 120.f));
    float Eo = exp2f_fast(-vo);
    float R2 = rcpf((1.f+Eo)*(1.f+Ec));
    return (1.f - Ec) * R2;
}

__device__ __forceinline__ uint16_t f2h(float f){
    union{ _Float16 h; uint16_t u; } v; v.h = (_Float16)f;   // v_cvt_f16_f32 RNE
    return v.u;
}

// qsum: sum over lanes ^16 and ^32 on the VALU pipe (permlane swaps, R12-
// proven); fallback = proven shfl chain. Same pair-sum order either way.
__device__ __forceinline__ float qsum(float x){
#if __has_builtin(__builtin_amdgcn_permlane16_swap) && __has_builtin(__builtin_amdgcn_permlane32_swap)
    unsigned int xi = __float_as_uint(x);
    auto p = __builtin_amdgcn_permlane16_swap(xi, xi, false, false);
    float s = __uint_as_float(p[0]) + __uint_as_float(p[1]);
    unsigned int si = __float_as_uint(s);
    auto q = __builtin_amdgcn_permlane32_swap(si, si, false, false);
    return __uint_as_float(q[0]) + __uint_as_float(q[1]);
#else
    x += __shfl_xor(x, 16, 64);
    x += __shfl_xor(x, 32, 64);
    return x;
#endif
}
#define MFMA __builtin_amdgcn_mfma_f32_16x16x32_f16

// R28 = R12 with the out-writer on wave 11. Evidence: waves map to SIMDs by
// wv%4; R13 (writer=wave13, SIMD1 {1,5,9,13} = heaviest, 4 waves) cost 20us
// vs R12 (writer=wave6, SIMD2 {2,6,10}, but wave 6 is an L2 wave = longest
// chain). Wave 11: L1 role (short chain, idle in future phase 1) AND SIMD3
// {3,7,11} (lightest, load 4->4.5). Everything else byte-identical to R12.
__global__ __launch_bounds__(BLK, 1)
void lstm_f16r2(const float* __restrict__ inp,    // [B, Tin]
                const float* __restrict__ Wih1,   // [204, 1]
                const float* __restrict__ Whh1,   // [204, 51]
                const float* __restrict__ bih1,   // [204]
                const float* __restrict__ bhh1,   // [204]
                const float* __restrict__ Wih2,   // [204, 51]
                const float* __restrict__ Whh2,   // [204, 51]
                const float* __restrict__ bih2,   // [204]
                const float* __restrict__ bhh2,   // [204]
                const float* __restrict__ Wl,     // [1, 51]
                const float* __restrict__ blp,    // [1]
                float* __restrict__ outp)         // [B, Ttot]
{
    const int tid = threadIdx.x;
    const int wv  = tid >> 6, ln = tid & 63;
    const int quad = ln >> 4, nn = ln & 15;
    const bool lo = (nn < 8);
    const int ba  = nn & 7;            // batch owned/read by this lane
    const int b0  = blockIdx.x * NBB;
    const bool isL2 = (wv < NTP);      // role: L2(t) vs L1(t+1)
    const int  wvv  = isL2 ? wv : wv - NTP;

    __shared__ __align__(16) uint16_t Bh[2][BROWS*BST];
    __shared__ float wsum[2][NTP*WS];     // parity-dbuf output partials

    for (int k = tid; k < BROWS*BST; k += BLK) { Bh[0][k] = 0; Bh[1][k] = 0; }
    if (tid < NTP*WS) { wsum[0][tid] = 0.f; wsum[1][tid] = 0.f; }

    // ---- A fragments, role-unioned: L2 uses af[tl*4+s] (s=0..3, Wih2|Whh2);
    // L1 uses af[tl*2+s] (s=0..1, Whh1). bs = role bias; w1v/wlu role-only. ----
    half8 af[8];
    f32x4 bs[2], w1v[2];
    float wlu[2];
#pragma unroll
    for (int tl = 0; tl < 2; ++tl) {
        const bool tv = (wvv + 7*tl) < 13;
        const int lr = 16*(wvv + 7*tl) + nn;
        const int ua_ = lr >> 2, ga = lr & 3;
        const bool av = tv && (ua_ < Hh);
        const int pr = av ? (ga*Hh + ua_) : 0;
        const float rs = (ga == 2) ? TL2E : L2E;
        if (isL2) {
#pragma unroll
            for (int s = 0; s < 4; ++s)
#pragma unroll
                for (int j = 0; j < 8; ++j) {
                    int k = 32*s + quad*8 + j;
                    float w = 0.f;
                    if (av) {
                        if (k < Hh)                    w = Wih2[pr*Hh + k]*rs;
                        else if (k >= 64 && k < 64+Hh) w = Whh2[pr*Hh + (k-64)]*rs;
                    }
                    af[tl*4+s][j] = (_Float16)w;
                }
        } else {
#pragma unroll
            for (int s = 0; s < 2; ++s)
#pragma unroll
                for (int j = 0; j < 8; ++j) {
                    int k = 32*s + quad*8 + j;
                    float w = (av && k < Hh) ? Whh1[pr*Hh + k]*rs : 0.f;
                    af[tl*2+s][j] = (_Float16)w;
                }
        }
        const int u = 4*(wvv + 7*tl) + quad;
        const bool uv = tv && (u < Hh);
#pragma unroll
        for (int i = 0; i < 4; ++i) {
            int pri = uv ? (i*Hh + u) : 0;
            float gs = (i == 2) ? TL2E : L2E;
            if (isL2) {
                bs[tl][i]  = uv ? (bih2[pri] + bhh2[pri])*gs : 0.f;
                w1v[tl][i] = 0.f;
            } else {
                bs[tl][i]  = uv ? (bih1[pri] + bhh1[pri])*gs : 0.f;
                w1v[tl][i] = uv ? Wih1[pri]*gs : 0.f;
            }
        }
        wlu[tl] = (isL2 && uv) ? Wl[u] : 0.f;
    }
    const float blv = blp[0];

    // ---- assigned cell for this lane: (ua, ba); role c-state lives here ----
    const int  ua  = 4*(wvv + (lo ? 0 : 7)) + quad;
    const bool uva = (ua < Hh);
    const float wlua = lo ? wlu[0] : wlu[1];
    float cst = 0.f;                    // c2 for L2 waves, c1 for L1 waves

    // ---- prologue: h1(0) by L1 waves (they own c1) ----
    if (!isL2) {
        float b1a[4], w1a[4];
#pragma unroll
        for (int i = 0; i < 4; ++i) {
            b1a[i] = lo ? bs[0][i] : bs[1][i];
            w1a[i] = lo ? w1v[0][i] : w1v[1][i];
        }
        float x0 = inp[(size_t)(b0 + ba)*Tin];
        float vi = __builtin_fmaf(w1a[0], x0, b1a[0]);
        float vf = __builtin_fmaf(w1a[1], x0, b1a[1]);
        float vg = __builtin_fmaf(w1a[2], x0, b1a[2]);
        float vo = __builtin_fmaf(w1a[3], x0, b1a[3]);
        float h1n = cell_fuse(vi, vf, vg, vo, cst);
        if (uva) Bh[0][ba*BST + ua] = f2h(h1n);
    }
    float xreg = (!isL2 && Tin > 1) ? inp[(size_t)(b0 + ba)*Tin + 1] : 0.f;
    __syncthreads();

    // ================= input-mode loop: t in [0, Tin-1) =================
    for (int t = 0; t < Tin-1; ++t) {
        const int cur = t & 1, nxt = cur ^ 1;

        // ---- B-frag reads first; L1 waves only need slabs 0,1 ----
        const uint16_t* rb = &Bh[cur][ba*BST + quad*8];
        half8 s0 = *(const half8*)(rb), s1 = *(const half8*)(rb + 32);
        half8 s2, s3;
        if (isL2) { s2 = *(const half8*)(rb + 64); s3 = *(const half8*)(rb + 96); }

        // out(t-1) write (wave 11: L1 role on the lightest SIMD)
        if (wv == OUTW && t > 0) {
            float osum = blv;
#pragma unroll
            for (int w = 0; w < NTP; ++w)
                osum += wsum[nxt][w*WS + ba] + wsum[nxt][w*WS + 8 + ba];
            if (ln < NBB) outp[(size_t)(b0 + ln)*Ttot + (t-1)] = osum;
        }
        float xn = (!isL2 && t + 2 < Tin) ? inp[(size_t)(b0 + ba)*Tin + t + 2] : 0.f;

        if (isL2) {
            // ---- L2(t): 8 MFMA, h2 cell, wsum partial ----
            f32x4 aA0 = bs[0], aB0 = {0.f,0.f,0.f,0.f};
            f32x4 aA1 = bs[1], aB1 = {0.f,0.f,0.f,0.f};
            aA0 = MFMA(af[0], s0, aA0, 0,0,0);  aB0 = MFMA(af[1], s1, aB0, 0,0,0);
            aA1 = MFMA(af[4], s0, aA1, 0,0,0);  aB1 = MFMA(af[5], s1, aB1, 0,0,0);
            aA0 = MFMA(af[2], s2, aA0, 0,0,0);  aB0 = MFMA(af[3], s3, aB0, 0,0,0);
            aA1 = MFMA(af[6], s2, aA1, 0,0,0);  aB1 = MFMA(af[7], s3, aB1, 0,0,0);
            f32x4 gt0 = aA0 + aB0, gt1 = aA1 + aB1;
            float g[4];
#pragma unroll
            for (int i = 0; i < 4; ++i) g[i] = lo ? gt0[i] : gt1[i];
            float h2v = cell_fuse(g[0], g[1], g[2], g[3], cst);
            if (uva) Bh[nxt][ba*BST + 64 + ua] = f2h(h2v);
            float part = qsum(wlua * h2v);
            if (ln < 16) wsum[cur][wvv*WS + ln] = part;
        } else {
            // ---- L1(t+1): 4 MFMA, h1 cell ----
            f32x4 bA0, bA1, bB0 = {0.f,0.f,0.f,0.f}, bB1 = {0.f,0.f,0.f,0.f};
#pragma unroll
            for (int i = 0; i < 4; ++i) {
                bA0[i] = __builtin_fmaf(w1v[0][i], xreg, bs[0][i]);
                bA1[i] = __builtin_fmaf(w1v[1][i], xreg, bs[1][i]);
            }
            bA0 = MFMA(af[0], s0, bA0, 0,0,0);  bB0 = MFMA(af[1], s1, bB0, 0,0,0);
            bA1 = MFMA(af[2], s0, bA1, 0,0,0);  bB1 = MFMA(af[3], s1, bB1, 0,0,0);
            f32x4 gt0 = bA0 + bB0, gt1 = bA1 + bB1;
            float g[4];
#pragma unroll
            for (int i = 0; i < 4; ++i) g[i] = lo ? gt0[i] : gt1[i];
            float h1v = cell_fuse(g[0], g[1], g[2], g[3], cst);
            if (uva) Bh[nxt][ba*BST + ua] = f2h(h1v);
        }

        __syncthreads();
        xreg = xn;
    }

    // ================= future loop: t in [Tin-1, Ttot) =================
    for (int t = Tin-1; t < Ttot; ++t) {
        const int cur = t & 1, nxt = cur ^ 1;

        const uint16_t* rb = &Bh[cur][ba*BST + quad*8];
        half8 s0 = *(const half8*)(rb), s1 = *(const half8*)(rb + 32);
        half8 s2, s3;
        if (isL2) { s2 = *(const half8*)(rb + 64); s3 = *(const half8*)(rb + 96); }

        // out(t-1) by wave 11 -- L1 role idles in phase 1, free overlap
        if (wv == OUTW) {       // t >= 511 > 0 always
            float osum = blv;
#pragma unroll
            for (int w = 0; w < NTP; ++w)
                osum += wsum[nxt][w*WS + ba] + wsum[nxt][w*WS + 8 + ba];
            if (ln < NBB) outp[(size_t)(b0 + ln)*Ttot + (t-1)] = osum;
        }

        if (isL2) {
            f32x4 aA0 = bs[0], aB0 = {0.f,0.f,0.f,0.f};
            f32x4 aA1 = bs[1], aB1 = {0.f,0.f,0.f,0.f};
            aA0 = MFMA(af[0], s0, aA0, 0,0,0);  aB0 = MFMA(af[1], s1, aB0, 0,0,0);
            aA1 = MFMA(af[4], s0, aA1, 0,0,0);  aB1 = MFMA(af[5], s1, aB1, 0,0,0);
            aA0 = MFMA(af[2], s2, aA0, 0,0,0);  aB0 = MFMA(af[3], s3, aB0, 0,0,0);
            aA1 = MFMA(af[6], s2, aA1, 0,0,0);  aB1 = MFMA(af[7], s3, aB1, 0,0,0);
            f32x4 gt0 = aA0 + aB0, gt1 = aA1 + aB1;
            float g[4];
#pragma unroll
            for (int i = 0; i < 4; ++i) g[i] = lo ? gt0[i] : gt1[i];
            float h2v = cell_fuse(g[0], g[1], g[2], g[3], cst);
            if (uva) Bh[nxt][ba*BST + 64 + ua] = f2h(h2v);
            float part = qsum(wlua * h2v);
            if (ln < 16) wsum[cur][wvv*WS + ln] = part;
        }
        __syncthreads();                                   // bar 1

        if (t + 1 < Ttot) {
            if (!isL2) {
                // x(t+1) = out(t) from wsum[cur], then L1(t+1)
                float osum = blv;
#pragma unroll
                for (int w = 0; w < NTP; ++w)
                    osum += wsum[cur][w*WS + ba] + wsum[cur][w*WS + 8 + ba];
                f32x4 bA0, bA1, bB0 = {0.f,0.f,0.f,0.f}, bB1 = {0.f,0.f,0.f,0.f};
#pragma unroll
                for (int i = 0; i < 4; ++i) {
                    bA0[i] = __builtin_fmaf(w1v[0][i], osum, bs[0][i]);
                    bA1[i] = __builtin_fmaf(w1v[1][i], osum, bs[1][i]);
                }
                bA0 = MFMA(af[0], s0, bA0, 0,0,0);  bB0 = MFMA(af[1], s1, bB0, 0,0,0);
                bA1 = MFMA(af[2], s0, bA1, 0,0,0);  bB1 = MFMA(af[3], s1, bB1, 0,0,0);
                f32x4 gt0 = bA0 + bB0, gt1 = bA1 + bB1;
                float g[4];
#pragma unroll
                for (int i = 0; i < 4; ++i) g[i] = lo ? gt0[i] : gt1[i];
                float h1v = cell_fuse(g[0], g[1], g[2], g[3], cst);
                if (uva) Bh[nxt][ba*BST + ua] = f2h(h1v);
            }
            __syncthreads();                               // bar 2 (future only)
        }
    }

    // final output (t = Ttot-1): wsum[(Ttot-1)&1] visible after last bar 1
    if (wv == OUTW) {
        float osum = blv;
#pragma unroll
        for (int w = 0; w < NTP; ++w)
            osum += wsum[(Ttot-1)&1][w*WS + ba] + wsum[(Ttot-1)&1][w*WS + 8 + ba];
        if (ln < NBB) outp[(size_t)(b0 + ln)*Ttot + (Ttot-1)] = osum;
    }
}

extern "C" void kernel_launch(void* const* d_in, const int* in_sizes, int n_in,
                              void* d_out, int out_size, void* d_ws, size_t ws_size,
                              hipStream_t stream) {
    (void)in_sizes; (void)n_in; (void)out_size; (void)d_ws; (void)ws_size;
    lstm_f16r2<<<dim3(Bsz / NBB), dim3(BLK), 0, stream>>>(
        (const float*)d_in[0], (const float*)d_in[1],
        (const float*)d_in[2], (const float*)d_in[3],
        (const float*)d_in[4], (const float*)d_in[5],
        (const float*)d_in[6], (const float*)d_in[7],
        (const float*)d_in[8], (const float*)d_in[9],
        (const float*)d_in[10], (float*)d_out);
}

// Round 15
// 480.892 us; speedup vs baseline: 1.0751x; 1.0107x over previous
//
#include <hip/hip_runtime.h>
#include <stdint.h>

#define Hh    51
#define Bsz   1024
#define Tin   512
#define Ttot  576      // Tin + future(64)
#define NBB   8        // batches per block (grid 128)
#define BROWS 8        // LDS batch rows (mirror trick: cols 8-15 read row nn&7)
#define NTP   7        // tile-pairs (13 M-tiles in 7 pairs)
#define NWV   14       // 7 L2 waves + 7 L1 waves (layer-split specialization)
#define BLK   (NWV*64) // 896
#define BST   136      // per-batch k-stride (uint16) = 68 dwords
#define WS    18       // wsum per-wave stride (16 partials + 2 pad)
#define OUTW  11       // out-writer wave: L1 role, SIMD3 (lightest: waves 3,7,11)

#define L2E   1.4426950408889634f    // log2(e)
#define TL2E  2.8853900817779268f    // 2*log2(e)

typedef __attribute__((ext_vector_type(8))) _Float16 half8;  // 8 x f16 frag
typedef __attribute__((ext_vector_type(4))) float f32x4;     // C/D frag

__device__ __forceinline__ float rcpf(float x){ return __builtin_amdgcn_rcpf(x); }
__device__ __forceinline__ float exp2f_fast(float x){
#if __has_builtin(__builtin_amdgcn_exp2f)
    return __builtin_amdgcn_exp2f(x);
#else
    return exp2f(x);
#endif
}

// Fused LSTM pointwise, rcp-merged: 7 trans ops.
// Inputs pre-scaled: vi,vf,vo by log2e; vg by 2log2e. Updates c, returns h.
__device__ __forceinline__ float cell_fuse(float vi, float vf, float vg,
                                           float vo, float& c){
    float Ei = exp2f_fast(-vi), Ef = exp2f_fast(-vf), Eg = exp2f_fast(-vg);
    float A = 1.f + Ef, B = 1.f + Ei, C = 1.f + Eg, D = 1.f - Eg;
    float BC = B*C;
    float R  = rcpf(A*BC);
    float cn = __builtin_fmaf(c, BC*R, (A*D)*R);
    c = cn;
    float Ec = exp2f_fast(fminf(-cn*TL2E, 120.f));
    float Eo = exp2f_fast(-vo);
    float R2 = rcpf((1.f+Eo)*(1.f+Ec));
    return (1.f - Ec) * R2;
}

__device__ __forceinline__ uint16_t f2h(float f){
    union{ _Float16 h; uint16_t u; } v; v.h = (_Float16)f;   // v_cvt_f16_f32 RNE
    return v.u;
}

// qsum: sum over lanes ^16 and ^32 on the VALU pipe (permlane swaps, R12-
// proven); fallback = proven shfl chain. Same pair-sum order either way.
__device__ __forceinline__ float qsum(float x){
#if __has_builtin(__builtin_amdgcn_permlane16_swap) && __has_builtin(__builtin_amdgcn_permlane32_swap)
    unsigned int xi = __float_as_uint(x);
    auto p = __builtin_amdgcn_permlane16_swap(xi, xi, false, false);
    float s = __uint_as_float(p[0]) + __uint_as_float(p[1]);
    unsigned int si = __float_as_uint(s);
    auto q = __builtin_amdgcn_permlane32_swap(si, si, false, false);
    return __uint_as_float(q[0]) + __uint_as_float(q[1]);
#else
    x += __shfl_xor(x, 16, 64);
    x += __shfl_xor(x, 32, 64);
    return x;
#endif
}
#define MFMA __builtin_amdgcn_mfma_f32_16x16x32_f16

// R29 = R14 + persistent role-asymmetric s_setprio: L2 waves (the critical
// chain -- 4 slabs, 8 MFMA, cell, qsum; barrier quantum = their completion)
// run at priority 1 for the whole kernel; L1 waves stay at 0 and fill L2's
// dependency bubbles. T5 evidence: null on lockstep (m190) but +21-39% on
// role-split schedules (m218b/m224) -- we have a genuine role split since
// R10. L1 has ~half the work (~90 issue cy vs ~900 L2-stall cy/step), so
// lower priority cannot delay the barrier. Zero numerics change vs R14.
__global__ __launch_bounds__(BLK, 1)
void lstm_f16t2(const float* __restrict__ inp,    // [B, Tin]
                const float* __restrict__ Wih1,   // [204, 1]
                const float* __restrict__ Whh1,   // [204, 51]
                const float* __restrict__ bih1,   // [204]
                const float* __restrict__ bhh1,   // [204]
                const float* __restrict__ Wih2,   // [204, 51]
                const float* __restrict__ Whh2,   // [204, 51]
                const float* __restrict__ bih2,   // [204]
                const float* __restrict__ bhh2,   // [204]
                const float* __restrict__ Wl,     // [1, 51]
                const float* __restrict__ blp,    // [1]
                float* __restrict__ outp)         // [B, Ttot]
{
    const int tid = threadIdx.x;
    const int wv  = tid >> 6, ln = tid & 63;
    const int quad = ln >> 4, nn = ln & 15;
    const bool lo = (nn < 8);
    const int ba  = nn & 7;            // batch owned/read by this lane
    const int b0  = blockIdx.x * NBB;
    const bool isL2 = (wv < NTP);      // role: L2(t) vs L1(t+1)
    const int  wvv  = isL2 ? wv : wv - NTP;

    if (isL2) __builtin_amdgcn_s_setprio(1);   // critical-chain waves favored

    __shared__ __align__(16) uint16_t Bh[2][BROWS*BST];
    __shared__ float wsum[2][NTP*WS];     // parity-dbuf output partials

    for (int k = tid; k < BROWS*BST; k += BLK) { Bh[0][k] = 0; Bh[1][k] = 0; }
    if (tid < NTP*WS) { wsum[0][tid] = 0.f; wsum[1][tid] = 0.f; }

    // ---- A fragments, role-unioned: L2 uses af[tl*4+s] (s=0..3, Wih2|Whh2);
    // L1 uses af[tl*2+s] (s=0..1, Whh1). bs = role bias; w1v/wlu role-only. ----
    half8 af[8];
    f32x4 bs[2], w1v[2];
    float wlu[2];
#pragma unroll
    for (int tl = 0; tl < 2; ++tl) {
        const bool tv = (wvv + 7*tl) < 13;
        const int lr = 16*(wvv + 7*tl) + nn;
        const int ua_ = lr >> 2, ga = lr & 3;
        const bool av = tv && (ua_ < Hh);
        const int pr = av ? (ga*Hh + ua_) : 0;
        const float rs = (ga == 2) ? TL2E : L2E;
        if (isL2) {
#pragma unroll
            for (int s = 0; s < 4; ++s)
#pragma unroll
                for (int j = 0; j < 8; ++j) {
                    int k = 32*s + quad*8 + j;
                    float w = 0.f;
                    if (av) {
                        if (k < Hh)                    w = Wih2[pr*Hh + k]*rs;
                        else if (k >= 64 && k < 64+Hh) w = Whh2[pr*Hh + (k-64)]*rs;
                    }
                    af[tl*4+s][j] = (_Float16)w;
                }
        } else {
#pragma unroll
            for (int s = 0; s < 2; ++s)
#pragma unroll
                for (int j = 0; j < 8; ++j) {
                    int k = 32*s + quad*8 + j;
                    float w = (av && k < Hh) ? Whh1[pr*Hh + k]*rs : 0.f;
                    af[tl*2+s][j] = (_Float16)w;
                }
        }
        const int u = 4*(wvv + 7*tl) + quad;
        const bool uv = tv && (u < Hh);
#pragma unroll
        for (int i = 0; i < 4; ++i) {
            int pri = uv ? (i*Hh + u) : 0;
            float gs = (i == 2) ? TL2E : L2E;
            if (isL2) {
                bs[tl][i]  = uv ? (bih2[pri] + bhh2[pri])*gs : 0.f;
                w1v[tl][i] = 0.f;
            } else {
                bs[tl][i]  = uv ? (bih1[pri] + bhh1[pri])*gs : 0.f;
                w1v[tl][i] = uv ? Wih1[pri]*gs : 0.f;
            }
        }
        wlu[tl] = (isL2 && uv) ? Wl[u] : 0.f;
    }
    const float blv = blp[0];

    // ---- assigned cell for this lane: (ua, ba); role c-state lives here ----
    const int  ua  = 4*(wvv + (lo ? 0 : 7)) + quad;
    const bool uva = (ua < Hh);
    const float wlua = lo ? wlu[0] : wlu[1];
    float cst = 0.f;                    // c2 for L2 waves, c1 for L1 waves

    // ---- prologue: h1(0) by L1 waves (they own c1) ----
    if (!isL2) {
        float b1a[4], w1a[4];
#pragma unroll
        for (int i = 0; i < 4; ++i) {
            b1a[i] = lo ? bs[0][i] : bs[1][i];
            w1a[i] = lo ? w1v[0][i] : w1v[1][i];
        }
        float x0 = inp[(size_t)(b0 + ba)*Tin];
        float vi = __builtin_fmaf(w1a[0], x0, b1a[0]);
        float vf = __builtin_fmaf(w1a[1], x0, b1a[1]);
        float vg = __builtin_fmaf(w1a[2], x0, b1a[2]);
        float vo = __builtin_fmaf(w1a[3], x0, b1a[3]);
        float h1n = cell_fuse(vi, vf, vg, vo, cst);
        if (uva) Bh[0][ba*BST + ua] = f2h(h1n);
    }
    float xreg = (!isL2 && Tin > 1) ? inp[(size_t)(b0 + ba)*Tin + 1] : 0.f;
    __syncthreads();

    // ================= input-mode loop: t in [0, Tin-1) =================
    for (int t = 0; t < Tin-1; ++t) {
        const int cur = t & 1, nxt = cur ^ 1;

        // ---- B-frag reads first; L1 waves only need slabs 0,1 ----
        const uint16_t* rb = &Bh[cur][ba*BST + quad*8];
        half8 s0 = *(const half8*)(rb), s1 = *(const half8*)(rb + 32);
        half8 s2, s3;
        if (isL2) { s2 = *(const half8*)(rb + 64); s3 = *(const half8*)(rb + 96); }

        // out(t-1) write (wave 11: L1 role on the lightest SIMD)
        if (wv == OUTW && t > 0) {
            float osum = blv;
#pragma unroll
            for (int w = 0; w < NTP; ++w)
                osum += wsum[nxt][w*WS + ba] + wsum[nxt][w*WS + 8 + ba];
            if (ln < NBB) outp[(size_t)(b0 + ln)*Ttot + (t-1)] = osum;
        }
        float xn = (!isL2 && t + 2 < Tin) ? inp[(size_t)(b0 + ba)*Tin + t + 2] : 0.f;

        if (isL2) {
            // ---- L2(t): 8 MFMA, h2 cell, wsum partial ----
            f32x4 aA0 = bs[0], aB0 = {0.f,0.f,0.f,0.f};
            f32x4 aA1 = bs[1], aB1 = {0.f,0.f,0.f,0.f};
            aA0 = MFMA(af[0], s0, aA0, 0,0,0);  aB0 = MFMA(af[1], s1, aB0, 0,0,0);
            aA1 = MFMA(af[4], s0, aA1, 0,0,0);  aB1 = MFMA(af[5], s1, aB1, 0,0,0);
            aA0 = MFMA(af[2], s2, aA0, 0,0,0);  aB0 = MFMA(af[3], s3, aB0, 0,0,0);
            aA1 = MFMA(af[6], s2, aA1, 0,0,0);  aB1 = MFMA(af[7], s3, aB1, 0,0,0);
            f32x4 gt0 = aA0 + aB0, gt1 = aA1 + aB1;
            float g[4];
#pragma unroll
            for (int i = 0; i < 4; ++i) g[i] = lo ? gt0[i] : gt1[i];
            float h2v = cell_fuse(g[0], g[1], g[2], g[3], cst);
            if (uva) Bh[nxt][ba*BST + 64 + ua] = f2h(h2v);
            float part = qsum(wlua * h2v);
            if (ln < 16) wsum[cur][wvv*WS + ln] = part;
        } else {
            // ---- L1(t+1): 4 MFMA, h1 cell ----
            f32x4 bA0, bA1, bB0 = {0.f,0.f,0.f,0.f}, bB1 = {0.f,0.f,0.f,0.f};
#pragma unroll
            for (int i = 0; i < 4; ++i) {
                bA0[i] = __builtin_fmaf(w1v[0][i], xreg, bs[0][i]);
                bA1[i] = __builtin_fmaf(w1v[1][i], xreg, bs[1][i]);
            }
            bA0 = MFMA(af[0], s0, bA0, 0,0,0);  bB0 = MFMA(af[1], s1, bB0, 0,0,0);
            bA1 = MFMA(af[2], s0, bA1, 0,0,0);  bB1 = MFMA(af[3], s1, bB1, 0,0,0);
            f32x4 gt0 = bA0 + bB0, gt1 = bA1 + bB1;
            float g[4];
#pragma unroll
            for (int i = 0; i < 4; ++i) g[i] = lo ? gt0[i] : gt1[i];
            float h1v = cell_fuse(g[0], g[1], g[2], g[3], cst);
            if (uva) Bh[nxt][ba*BST + ua] = f2h(h1v);
        }

        __syncthreads();
        xreg = xn;
    }

    // ================= future loop: t in [Tin-1, Ttot) =================
    for (int t = Tin-1; t < Ttot; ++t) {
        const int cur = t & 1, nxt = cur ^ 1;

        const uint16_t* rb = &Bh[cur][ba*BST + quad*8];
        half8 s0 = *(const half8*)(rb), s1 = *(const half8*)(rb + 32);
        half8 s2, s3;
        if (isL2) { s2 = *(const half8*)(rb + 64); s3 = *(const half8*)(rb + 96); }

        // out(t-1) by wave 11 -- L1 role idles in phase 1, free overlap
        if (wv == OUTW) {       // t >= 511 > 0 always
            float osum = blv;
#pragma unroll
            for (int w = 0; w < NTP; ++w)
                osum += wsum[nxt][w*WS + ba] + wsum[nxt][w*WS + 8 + ba];
            if (ln < NBB) outp[(size_t)(b0 + ln)*Ttot + (t-1)] = osum;
        }

        if (isL2) {
            f32x4 aA0 = bs[0], aB0 = {0.f,0.f,0.f,0.f};
            f32x4 aA1 = bs[1], aB1 = {0.f,0.f,0.f,0.f};
            aA0 = MFMA(af[0], s0, aA0, 0,0,0);  aB0 = MFMA(af[1], s1, aB0, 0,0,0);
            aA1 = MFMA(af[4], s0, aA1, 0,0,0);  aB1 = MFMA(af[5], s1, aB1, 0,0,0);
            aA0 = MFMA(af[2], s2, aA0, 0,0,0);  aB0 = MFMA(af[3], s3, aB0, 0,0,0);
            aA1 = MFMA(af[6], s2, aA1, 0,0,0);  aB1 = MFMA(af[7], s3, aB1, 0,0,0);
            f32x4 gt0 = aA0 + aB0, gt1 = aA1 + aB1;
            float g[4];
#pragma unroll
            for (int i = 0; i < 4; ++i) g[i] = lo ? gt0[i] : gt1[i];
            float h2v = cell_fuse(g[0], g[1], g[2], g[3], cst);
            if (uva) Bh[nxt][ba*BST + 64 + ua] = f2h(h2v);
            float part = qsum(wlua * h2v);
            if (ln < 16) wsum[cur][wvv*WS + ln] = part;
        }
        __syncthreads();                                   // bar 1

        if (t + 1 < Ttot) {
            if (!isL2) {
                // x(t+1) = out(t) from wsum[cur], then L1(t+1)
                float osum = blv;
#pragma unroll
                for (int w = 0; w < NTP; ++w)
                    osum += wsum[cur][w*WS + ba] + wsum[cur][w*WS + 8 + ba];
                f32x4 bA0, bA1, bB0 = {0.f,0.f,0.f,0.f}, bB1 = {0.f,0.f,0.f,0.f};
#pragma unroll
                for (int i = 0; i < 4; ++i) {
                    bA0[i] = __builtin_fmaf(w1v[0][i], osum, bs[0][i]);
                    bA1[i] = __builtin_fmaf(w1v[1][i], osum, bs[1][i]);
                }
                bA0 = MFMA(af[0], s0, bA0, 0,0,0);  bB0 = MFMA(af[1], s1, bB0, 0,0,0);
                bA1 = MFMA(af[2], s0, bA1, 0,0,0);  bB1 = MFMA(af[3], s1, bB1, 0,0,0);
                f32x4 gt0 = bA0 + bB0, gt1 = bA1 + bB1;
                float g[4];
#pragma unroll
                for (int i = 0; i < 4; ++i) g[i] = lo ? gt0[i] : gt1[i];
                float h1v = cell_fuse(g[0], g[1], g[2], g[3], cst);
                if (uva) Bh[nxt][ba*BST + ua] = f2h(h1v);
            }
            __syncthreads();                               // bar 2 (future only)
        }
    }

    // final output (t = Ttot-1): wsum[(Ttot-1)&1] visible after last bar 1
    if (wv == OUTW) {
        float osum = blv;
#pragma unroll
        for (int w = 0; w < NTP; ++w)
            osum += wsum[(Ttot-1)&1][w*WS + ba] + wsum[(Ttot-1)&1][w*WS + 8 + ba];
        if (ln < NBB) outp[(size_t)(b0 + ln)*Ttot + (Ttot-1)] = osum;
    }
}

extern "C" void kernel_launch(void* const* d_in, const int* in_sizes, int n_in,
                              void* d_out, int out_size, void* d_ws, size_t ws_size,
                              hipStream_t stream) {
    (void)in_sizes; (void)n_in; (void)out_size; (void)d_ws; (void)ws_size;
    lstm_f16t2<<<dim3(Bsz / NBB), dim3(BLK), 0, stream>>>(
        (const float*)d_in[0], (const float*)d_in[1],
        (const float*)d_in[2], (const float*)d_in[3],
        (const float*)d_in[4], (const float*)d_in[5],
        (const float*)d_in[6], (const float*)d_in[7],
        (const float*)d_in[8], (const float*)d_in[9],
        (const float*)d_in[10], (float*)d_out);
}

// Round 16
// 478.943 us; speedup vs baseline: 1.0794x; 1.0041x over previous
//
#include <hip/hip_runtime.h>
#include <stdint.h>

#define Hh    51
#define Bsz   1024
#define Tin   512
#define Ttot  576      // Tin + future(64)
#define NBB   8        // batches per block (grid 128)
#define BROWS 8        // LDS batch rows (mirror trick: cols 8-15 read row nn&7)
#define NTP   7        // tile-pairs (13 M-tiles in 7 pairs)
#define NWV   14       // 7 L2 waves + 7 L1 waves (layer-split specialization)
#define BLK   (NWV*64) // 896
#define BST   136      // per-batch k-stride (uint16) = 68 dwords
#define WS    18       // wsum per-wave stride (16 partials + 2 pad)
#define OUTW  11       // out-writer wave: L1 role, SIMD3 (lightest)
#define L2MASK 0x4CFu  // L2 waves {0,1,2,3,6,7,10}: per-SIMD L2 counts (1,1,3,2)

#define L2E   1.4426950408889634f    // log2(e)
#define TL2E  2.8853900817779268f    // 2*log2(e)

typedef __attribute__((ext_vector_type(8))) _Float16 half8;  // 8 x f16 frag
typedef __attribute__((ext_vector_type(4))) float f32x4;     // C/D frag

__device__ __forceinline__ float rcpf(float x){ return __builtin_amdgcn_rcpf(x); }
__device__ __forceinline__ float exp2f_fast(float x){
#if __has_builtin(__builtin_amdgcn_exp2f)
    return __builtin_amdgcn_exp2f(x);
#else
    return exp2f(x);
#endif
}

// Fused LSTM pointwise, rcp-merged: 7 trans ops.
// Inputs pre-scaled: vi,vf,vo by log2e; vg by 2log2e. Updates c, returns h.
__device__ __forceinline__ float cell_fuse(float vi, float vf, float vg,
                                           float vo, float& c){
    float Ei = exp2f_fast(-vi), Ef = exp2f_fast(-vf), Eg = exp2f_fast(-vg);
    float A = 1.f + Ef, B = 1.f + Ei, C = 1.f + Eg, D = 1.f - Eg;
    float BC = B*C;
    float R  = rcpf(A*BC);
    float cn = __builtin_fmaf(c, BC*R, (A*D)*R);
    c = cn;
    float Ec = exp2f_fast(fminf(-cn*TL2E, 120.f));
    float Eo = exp2f_fast(-vo);
    float R2 = rcpf((1.f+Eo)*(1.f+Ec));
    return (1.f - Ec) * R2;
}

__device__ __forceinline__ uint16_t f2h(float f){
    union{ _Float16 h; uint16_t u; } v; v.h = (_Float16)f;   // v_cvt_f16_f32 RNE
    return v.u;
}

// qsum: sum over lanes ^16 and ^32 on the VALU pipe (permlane swaps, R12-
// proven); fallback = proven shfl chain. Same pair-sum order either way.
__device__ __forceinline__ float qsum(float x){
#if __has_builtin(__builtin_amdgcn_permlane16_swap) && __has_builtin(__builtin_amdgcn_permlane32_swap)
    unsigned int xi = __float_as_uint(x);
    auto p = __builtin_amdgcn_permlane16_swap(xi, xi, false, false);
    float s = __uint_as_float(p[0]) + __uint_as_float(p[1]);
    unsigned int si = __float_as_uint(s);
    auto q = __builtin_amdgcn_permlane32_swap(si, si, false, false);
    return __uint_as_float(q[0]) + __uint_as_float(q[1]);
#else
    x += __shfl_xor(x, 16, 64);
    x += __shfl_xor(x, 32, 64);
    return x;
#endif
}
#define MFMA __builtin_amdgcn_mfma_f32_16x16x32_f16

// R30 = R29 + role-to-SIMD rebalance. R13/R14 proved per-SIMD issue load
// sets the barrier quantum. Old map (isL2 = wv<7) put 2 L2 + 2 L1 on each
// 4-wave SIMD (peak issue ~696 cy/step). New map: L2 waves = {0,1,2,3,6,
// 7,10} (mask 0x4CF) -> per-SIMD L2 counts (1,1,3,2), loads (632,632,618,
// 554): peak -9%. wvv = rank within role (popcount). Work per (role,wvv)
// unchanged -> outputs bit-identical. Writer stays wave 11 (L1, SIMD3).
__global__ __launch_bounds__(BLK, 1)
void lstm_f16u(const float* __restrict__ inp,    // [B, Tin]
               const float* __restrict__ Wih1,   // [204, 1]
               const float* __restrict__ Whh1,   // [204, 51]
               const float* __restrict__ bih1,   // [204]
               const float* __restrict__ bhh1,   // [204]
               const float* __restrict__ Wih2,   // [204, 51]
               const float* __restrict__ Whh2,   // [204, 51]
               const float* __restrict__ bih2,   // [204]
               const float* __restrict__ bhh2,   // [204]
               const float* __restrict__ Wl,     // [1, 51]
               const float* __restrict__ blp,    // [1]
               float* __restrict__ outp)         // [B, Ttot]
{
    const int tid = threadIdx.x;
    const int wv  = tid >> 6, ln = tid & 63;
    const int quad = ln >> 4, nn = ln & 15;
    const bool lo = (nn < 8);
    const int ba  = nn & 7;            // batch owned/read by this lane
    const int b0  = blockIdx.x * NBB;
    const bool isL2 = (L2MASK >> wv) & 1u;   // role: L2(t) vs L1(t+1)
    const unsigned below = (1u << wv) - 1u;
    const int  wvv  = isL2 ? __popc(L2MASK & below) : __popc(~L2MASK & below);

    if (isL2) __builtin_amdgcn_s_setprio(1);   // critical-chain waves favored

    __shared__ __align__(16) uint16_t Bh[2][BROWS*BST];
    __shared__ float wsum[2][NTP*WS];     // parity-dbuf output partials

    for (int k = tid; k < BROWS*BST; k += BLK) { Bh[0][k] = 0; Bh[1][k] = 0; }
    if (tid < NTP*WS) { wsum[0][tid] = 0.f; wsum[1][tid] = 0.f; }

    // ---- A fragments, role-unioned: L2 uses af[tl*4+s] (s=0..3, Wih2|Whh2);
    // L1 uses af[tl*2+s] (s=0..1, Whh1). bs = role bias; w1v/wlu role-only. ----
    half8 af[8];
    f32x4 bs[2], w1v[2];
    float wlu[2];
#pragma unroll
    for (int tl = 0; tl < 2; ++tl) {
        const bool tv = (wvv + 7*tl) < 13;
        const int lr = 16*(wvv + 7*tl) + nn;
        const int ua_ = lr >> 2, ga = lr & 3;
        const bool av = tv && (ua_ < Hh);
        const int pr = av ? (ga*Hh + ua_) : 0;
        const float rs = (ga == 2) ? TL2E : L2E;
        if (isL2) {
#pragma unroll
            for (int s = 0; s < 4; ++s)
#pragma unroll
                for (int j = 0; j < 8; ++j) {
                    int k = 32*s + quad*8 + j;
                    float w = 0.f;
                    if (av) {
                        if (k < Hh)                    w = Wih2[pr*Hh + k]*rs;
                        else if (k >= 64 && k < 64+Hh) w = Whh2[pr*Hh + (k-64)]*rs;
                    }
                    af[tl*4+s][j] = (_Float16)w;
                }
        } else {
#pragma unroll
            for (int s = 0; s < 2; ++s)
#pragma unroll
                for (int j = 0; j < 8; ++j) {
                    int k = 32*s + quad*8 + j;
                    float w = (av && k < Hh) ? Whh1[pr*Hh + k]*rs : 0.f;
                    af[tl*2+s][j] = (_Float16)w;
                }
        }
        const int u = 4*(wvv + 7*tl) + quad;
        const bool uv = tv && (u < Hh);
#pragma unroll
        for (int i = 0; i < 4; ++i) {
            int pri = uv ? (i*Hh + u) : 0;
            float gs = (i == 2) ? TL2E : L2E;
            if (isL2) {
                bs[tl][i]  = uv ? (bih2[pri] + bhh2[pri])*gs : 0.f;
                w1v[tl][i] = 0.f;
            } else {
                bs[tl][i]  = uv ? (bih1[pri] + bhh1[pri])*gs : 0.f;
                w1v[tl][i] = uv ? Wih1[pri]*gs : 0.f;
            }
        }
        wlu[tl] = (isL2 && uv) ? Wl[u] : 0.f;
    }
    const float blv = blp[0];

    // ---- assigned cell for this lane: (ua, ba); role c-state lives here ----
    const int  ua  = 4*(wvv + (lo ? 0 : 7)) + quad;
    const bool uva = (ua < Hh);
    const float wlua = lo ? wlu[0] : wlu[1];
    float cst = 0.f;                    // c2 for L2 waves, c1 for L1 waves

    // ---- prologue: h1(0) by L1 waves (they own c1) ----
    if (!isL2) {
        float b1a[4], w1a[4];
#pragma unroll
        for (int i = 0; i < 4; ++i) {
            b1a[i] = lo ? bs[0][i] : bs[1][i];
            w1a[i] = lo ? w1v[0][i] : w1v[1][i];
        }
        float x0 = inp[(size_t)(b0 + ba)*Tin];
        float vi = __builtin_fmaf(w1a[0], x0, b1a[0]);
        float vf = __builtin_fmaf(w1a[1], x0, b1a[1]);
        float vg = __builtin_fmaf(w1a[2], x0, b1a[2]);
        float vo = __builtin_fmaf(w1a[3], x0, b1a[3]);
        float h1n = cell_fuse(vi, vf, vg, vo, cst);
        if (uva) Bh[0][ba*BST + ua] = f2h(h1n);
    }
    float xreg = (!isL2 && Tin > 1) ? inp[(size_t)(b0 + ba)*Tin + 1] : 0.f;
    __syncthreads();

    // ================= input-mode loop: t in [0, Tin-1) =================
    for (int t = 0; t < Tin-1; ++t) {
        const int cur = t & 1, nxt = cur ^ 1;

        // ---- B-frag reads first; L1 waves only need slabs 0,1 ----
        const uint16_t* rb = &Bh[cur][ba*BST + quad*8];
        half8 s0 = *(const half8*)(rb), s1 = *(const half8*)(rb + 32);
        half8 s2, s3;
        if (isL2) { s2 = *(const half8*)(rb + 64); s3 = *(const half8*)(rb + 96); }

        // out(t-1) write (wave 11: L1 role on the lightest SIMD)
        if (wv == OUTW && t > 0) {
            float osum = blv;
#pragma unroll
            for (int w = 0; w < NTP; ++w)
                osum += wsum[nxt][w*WS + ba] + wsum[nxt][w*WS + 8 + ba];
            if (ln < NBB) outp[(size_t)(b0 + ln)*Ttot + (t-1)] = osum;
        }
        float xn = (!isL2 && t + 2 < Tin) ? inp[(size_t)(b0 + ba)*Tin + t + 2] : 0.f;

        if (isL2) {
            // ---- L2(t): 8 MFMA, h2 cell, wsum partial ----
            f32x4 aA0 = bs[0], aB0 = {0.f,0.f,0.f,0.f};
            f32x4 aA1 = bs[1], aB1 = {0.f,0.f,0.f,0.f};
            aA0 = MFMA(af[0], s0, aA0, 0,0,0);  aB0 = MFMA(af[1], s1, aB0, 0,0,0);
            aA1 = MFMA(af[4], s0, aA1, 0,0,0);  aB1 = MFMA(af[5], s1, aB1, 0,0,0);
            aA0 = MFMA(af[2], s2, aA0, 0,0,0);  aB0 = MFMA(af[3], s3, aB0, 0,0,0);
            aA1 = MFMA(af[6], s2, aA1, 0,0,0);  aB1 = MFMA(af[7], s3, aB1, 0,0,0);
            f32x4 gt0 = aA0 + aB0, gt1 = aA1 + aB1;
            float g[4];
#pragma unroll
            for (int i = 0; i < 4; ++i) g[i] = lo ? gt0[i] : gt1[i];
            float h2v = cell_fuse(g[0], g[1], g[2], g[3], cst);
            if (uva) Bh[nxt][ba*BST + 64 + ua] = f2h(h2v);
            float part = qsum(wlua * h2v);
            if (ln < 16) wsum[cur][wvv*WS + ln] = part;
        } else {
            // ---- L1(t+1): 4 MFMA, h1 cell ----
            f32x4 bA0, bA1, bB0 = {0.f,0.f,0.f,0.f}, bB1 = {0.f,0.f,0.f,0.f};
#pragma unroll
            for (int i = 0; i < 4; ++i) {
                bA0[i] = __builtin_fmaf(w1v[0][i], xreg, bs[0][i]);
                bA1[i] = __builtin_fmaf(w1v[1][i], xreg, bs[1][i]);
            }
            bA0 = MFMA(af[0], s0, bA0, 0,0,0);  bB0 = MFMA(af[1], s1, bB0, 0,0,0);
            bA1 = MFMA(af[2], s0, bA1, 0,0,0);  bB1 = MFMA(af[3], s1, bB1, 0,0,0);
            f32x4 gt0 = bA0 + bB0, gt1 = bA1 + bB1;
            float g[4];
#pragma unroll
            for (int i = 0; i < 4; ++i) g[i] = lo ? gt0[i] : gt1[i];
            float h1v = cell_fuse(g[0], g[1], g[2], g[3], cst);
            if (uva) Bh[nxt][ba*BST + ua] = f2h(h1v);
        }

        __syncthreads();
        xreg = xn;
    }

    // ================= future loop: t in [Tin-1, Ttot) =================
    for (int t = Tin-1; t < Ttot; ++t) {
        const int cur = t & 1, nxt = cur ^ 1;

        const uint16_t* rb = &Bh[cur][ba*BST + quad*8];
        half8 s0 = *(const half8*)(rb), s1 = *(const half8*)(rb + 32);
        half8 s2, s3;
        if (isL2) { s2 = *(const half8*)(rb + 64); s3 = *(const half8*)(rb + 96); }

        // out(t-1) by wave 11 -- L1 role idles in phase 1, free overlap
        if (wv == OUTW) {       // t >= 511 > 0 always
            float osum = blv;
#pragma unroll
            for (int w = 0; w < NTP; ++w)
                osum += wsum[nxt][w*WS + ba] + wsum[nxt][w*WS + 8 + ba];
            if (ln < NBB) outp[(size_t)(b0 + ln)*Ttot + (t-1)] = osum;
        }

        if (isL2) {
            f32x4 aA0 = bs[0], aB0 = {0.f,0.f,0.f,0.f};
            f32x4 aA1 = bs[1], aB1 = {0.f,0.f,0.f,0.f};
            aA0 = MFMA(af[0], s0, aA0, 0,0,0);  aB0 = MFMA(af[1], s1, aB0, 0,0,0);
            aA1 = MFMA(af[4], s0, aA1, 0,0,0);  aB1 = MFMA(af[5], s1, aB1, 0,0,0);
            aA0 = MFMA(af[2], s2, aA0, 0,0,0);  aB0 = MFMA(af[3], s3, aB0, 0,0,0);
            aA1 = MFMA(af[6], s2, aA1, 0,0,0);  aB1 = MFMA(af[7], s3, aB1, 0,0,0);
            f32x4 gt0 = aA0 + aB0, gt1 = aA1 + aB1;
            float g[4];
#pragma unroll
            for (int i = 0; i < 4; ++i) g[i] = lo ? gt0[i] : gt1[i];
            float h2v = cell_fuse(g[0], g[1], g[2], g[3], cst);
            if (uva) Bh[nxt][ba*BST + 64 + ua] = f2h(h2v);
            float part = qsum(wlua * h2v);
            if (ln < 16) wsum[cur][wvv*WS + ln] = part;
        }
        __syncthreads();                                   // bar 1

        if (t + 1 < Ttot) {
            if (!isL2) {
                // x(t+1) = out(t) from wsum[cur], then L1(t+1)
                float osum = blv;
#pragma unroll
                for (int w = 0; w < NTP; ++w)
                    osum += wsum[cur][w*WS + ba] + wsum[cur][w*WS + 8 + ba];
                f32x4 bA0, bA1, bB0 = {0.f,0.f,0.f,0.f}, bB1 = {0.f,0.f,0.f,0.f};
#pragma unroll
                for (int i = 0; i < 4; ++i) {
                    bA0[i] = __builtin_fmaf(w1v[0][i], osum, bs[0][i]);
                    bA1[i] = __builtin_fmaf(w1v[1][i], osum, bs[1][i]);
                }
                bA0 = MFMA(af[0], s0, bA0, 0,0,0);  bB0 = MFMA(af[1], s1, bB0, 0,0,0);
                bA1 = MFMA(af[2], s0, bA1, 0,0,0);  bB1 = MFMA(af[3], s1, bB1, 0,0,0);
                f32x4 gt0 = bA0 + bB0, gt1 = bA1 + bB1;
                float g[4];
#pragma unroll
                for (int i = 0; i < 4; ++i) g[i] = lo ? gt0[i] : gt1[i];
                float h1v = cell_fuse(g[0], g[1], g[2], g[3], cst);
                if (uva) Bh[nxt][ba*BST + ua] = f2h(h1v);
            }
            __syncthreads();                               // bar 2 (future only)
        }
    }

    // final output (t = Ttot-1): wsum[(Ttot-1)&1] visible after last bar 1
    if (wv == OUTW) {
        float osum = blv;
#pragma unroll
        for (int w = 0; w < NTP; ++w)
            osum += wsum[(Ttot-1)&1][w*WS + ba] + wsum[(Ttot-1)&1][w*WS + 8 + ba];
        if (ln < NBB) outp[(size_t)(b0 + ln)*Ttot + (Ttot-1)] = osum;
    }
}

extern "C" void kernel_launch(void* const* d_in, const int* in_sizes, int n_in,
                              void* d_out, int out_size, void* d_ws, size_t ws_size,
                              hipStream_t stream) {
    (void)in_sizes; (void)n_in; (void)out_size; (void)d_ws; (void)ws_size;
    lstm_f16u<<<dim3(Bsz / NBB), dim3(BLK), 0, stream>>>(
        (const float*)d_in[0], (const float*)d_in[1],
        (const float*)d_in[2], (const float*)d_in[3],
        (const float*)d_in[4], (const float*)d_in[5],
        (const float*)d_in[6], (const float*)d_in[7],
        (const float*)d_in[8], (const float*)d_in[9],
        (const float*)d_in[10], (float*)d_out);
}